// Round 7
// baseline (144.161 us; speedup 1.0000x reference)
//
#include <hip/hip_runtime.h>
#include <math.h>

#define B_    4
#define TDEC  512
#define TENC  1024
#define H_    128
#define DT    4

// tanh(enc) repacked: [b][e:1024][g:32][j:4]  (thread owns 512B contiguous region)
__device__ float g_tetp[(size_t)B_ * TENC * 32 * 4];           // 2 MB
// per (row-tile, g) broadcast pack: [v4(4) td_d0..d3(16) vt_d0..d3(16)] = 36 f
__device__ float g_tdvt[(size_t)B_ * 128 * 32 * 36];           // 2.25 MB
__device__ float g_scr[(size_t)B_ * TDEC * TENC];              // 8 MB raw scores

struct TDVG { float4 v4, td0, td1, td2, td3, vt0, vt1, vt2, vt3; };

union F4 { float4 v; float f[4]; };

__device__ __forceinline__ float ftanh(float x) {
    float e = __expf(2.f * x);
    return fmaf(-2.f, __builtin_amdgcn_rcpf(e + 1.f), 1.f);
}

// z<4: transpose+tanh enc -> g_tetp.   z==4: TD rows + tdvt pack.
__global__ __launch_bounds__(256) void prep_kernel(const float* __restrict__ enc,
                                                   const float* __restrict__ dec,
                                                   const float* __restrict__ Ww,
                                                   const float* __restrict__ Wb,
                                                   const float* __restrict__ Vw) {
    const int z = blockIdx.z;
    const int tx = threadIdx.x, ty = threadIdx.y;
    if (z < B_) {
        __shared__ float tile[32][33];               // [e-local][h-local]
        const int e0 = blockIdx.x * 32, h0 = blockIdx.y * 32, b = z;
        const float* ep = enc + (size_t)b * TENC * H_;
        #pragma unroll
        for (int j = 0; j < 32; j += 8)
            tile[ty + j][tx] = ep[(size_t)(e0 + ty + j) * H_ + h0 + tx];
        __syncthreads();
        // thread (tx,ty): e = e0+tx, g = h0/4+ty, j = h&3 -> one float4 store
        const int g = (h0 >> 2) + ty, e = e0 + tx;
        float4 o;
        o.x = ftanh(tile[tx][4 * ty + 0]);
        o.y = ftanh(tile[tx][4 * ty + 1]);
        o.z = ftanh(tile[tx][4 * ty + 2]);
        o.w = ftanh(tile[tx][4 * ty + 3]);
        *(float4*)&g_tetp[(((size_t)b * TENC + e) * 32 + g) * 4] = o;
    } else {
        // 128 blocks x 16 rows: td = tanh(dec @ Ww^T + Wb); pack td & v*td
        __shared__ float ds[16][H_];
        const int t = ty * 32 + tx;
        const int blk = blockIdx.y * 32 + blockIdx.x;      // 0..127
        const int R0 = blk * 16;
        #pragma unroll
        for (int i = 0; i < 8; ++i) {
            const int f = t + 256 * i;
            ds[f >> 7][f & 127] = dec[(size_t)R0 * H_ + f];
        }
        __syncthreads();
        const int k = t & 127, dd = t >> 7;
        const float* wr = Ww + (size_t)k * H_;
        float s[8];
        #pragma unroll
        for (int j = 0; j < 8; ++j) s[j] = 0.f;
        for (int h = 0; h < H_; h += 4) {
            const float4 w4 = *(const float4*)(wr + h);
            #pragma unroll
            for (int j = 0; j < 8; ++j) {
                const float4 d4 = *(const float4*)&ds[dd + 2 * j][h];
                s[j] = fmaf(w4.x, d4.x, s[j]);
                s[j] = fmaf(w4.y, d4.y, s[j]);
                s[j] = fmaf(w4.z, d4.z, s[j]);
                s[j] = fmaf(w4.w, d4.w, s[j]);
            }
        }
        const float wb = Wb[k], vw = Vw[k];
        const int g = k >> 2, jj = k & 3;
        #pragma unroll
        for (int j = 0; j < 8; ++j) {
            const int rl = dd + 2 * j;
            const float td = ftanh(s[j] + wb);
            const size_t off = ((size_t)((R0 >> 2) + (rl >> 2)) * 32 + g) * 36;
            g_tdvt[off + 4 + (rl & 3) * 4 + jj] = td;
            g_tdvt[off + 20 + (rl & 3) * 4 + jj] = vw * td;
        }
        if (dd == 0) {
            #pragma unroll
            for (int dl = 0; dl < 4; ++dl)
                g_tdvt[((size_t)((R0 >> 2) + dl) * 32 + g) * 36 + jj] = vw;
        }
    }
}

// 4 h-terms combined into one rcp; every instr has <=1 SGPR operand
// (v4 forced into VGPRs per g; td/vt stay in SGPRs).
__device__ __forceinline__ float term4(const float4 td, const float4 vt, const float4 v4,
                                       const F4 te, float acc) {
    const float p0 = fmaf(td.x, te.f[0], 1.f);
    const float p1 = fmaf(td.y, te.f[1], 1.f);
    const float p2 = fmaf(td.z, te.f[2], 1.f);
    const float p3 = fmaf(td.w, te.f[3], 1.f);
    const float x0 = fmaf(v4.x, te.f[0], vt.x);
    const float x1 = fmaf(v4.y, te.f[1], vt.y);
    const float x2 = fmaf(v4.z, te.f[2], vt.z);
    const float x3 = fmaf(v4.w, te.f[3], vt.w);
    const float p01 = p0 * p1, p23 = p2 * p3;
    const float u = fmaf(x1, p0, x0 * p1);
    const float zz = fmaf(x3, p2, x2 * p3);
    const float num = fmaf(zz, p01, u * p23);
    return fmaf(num, __builtin_amdgcn_rcpf(p01 * p23), acc);
}

#define DALL(S, TE) do {                                                        \
    float4 v4v = S.v4;                                                          \
    asm volatile("" : "+v"(v4v.x), "+v"(v4v.y), "+v"(v4v.z), "+v"(v4v.w));      \
    acc0 = term4(S.td0, S.vt0, v4v, TE, acc0);                                  \
    acc1 = term4(S.td1, S.vt1, v4v, TE, acc1);                                  \
    acc2 = term4(S.td2, S.vt2, v4v, TE, acc2);                                  \
    acc3 = term4(S.td3, S.vt3, v4v, TE, acc3);                                  \
} while (0)

// grid 2048 = 512 row-tiles x 4 e-quarters; block 256 thr; thread owns 1 e.
// All te loads: dwordx4 with imm offsets off ONE base -> zero addr VALU in loop.
__global__ __launch_bounds__(256) void score_kernel() {
    const int t = threadIdx.x, blk = blockIdx.x;
    const int rt = blk >> 2, eq = blk & 3;
    const int b = rt >> 7;
    const int R0 = rt * DT;
    const TDVG* tp = (const TDVG*)g_tdvt + (size_t)rt * 32;
    const int e = eq * 256 + t;
    const float* teb = g_tetp + ((size_t)b * TENC + e) * 128;   // 512B region

    float acc0 = 0.f, acc1 = 0.f, acc2 = 0.f, acc3 = 0.f;

    TDVG A = tp[0];
    F4 tea; tea.v = *(const float4*)teb;

    for (int g = 0; g < 32; g += 2) {
        F4 teb4; teb4.v = *(const float4*)(teb + (g + 1) * 4);
        TDVG Bv = tp[g + 1];

        DALL(A, tea);

        const int gn = (g + 2) & 31;          // wrap instead of branch (last iter dummy)
        tea.v = *(const float4*)(teb + gn * 4);
        A = tp[gn];

        DALL(Bv, teb4);
    }

    float* so = g_scr + (size_t)R0 * TENC + eq * 256 + t;
    so[0 * TENC] = acc0;
    so[1 * TENC] = acc1;
    so[2 * TENC] = acc2;
    so[3 * TENC] = acc3;
}

// softmax + context: block = (b, row-tile of 4, h-half of 64); no max pass
// (|score| <= sum|V_h| ~ 9 -> exp safely in fp32 range; softmax shift-invariant).
__global__ __launch_bounds__(512, 8) void smctx_kernel(const float* __restrict__ enc,
                                                       float* __restrict__ out) {
    __shared__ float sc[DT][TENC];
    __shared__ float2 part[16][DT][33];
    __shared__ float sump[2][DT];
    const int t = threadIdx.x;
    const int blk = blockIdx.x;
    const int hh = blk & 1, dt = (blk >> 1) & 127, b = blk >> 8;
    const int R0 = b * TDEC + dt * DT;

    {
        const int w = t >> 6, lane = t & 63;
        const int d = w & 3, eh = w >> 2;
        const float* sr = g_scr + (size_t)(R0 + d) * TENC + eh * 512 + lane;
        float s = 0.f;
        #pragma unroll
        for (int i = 0; i < 8; ++i) {
            const float p = __expf(sr[i * 64]);
            sc[d][eh * 512 + lane + i * 64] = p;
            s += p;
        }
        #pragma unroll
        for (int off = 32; off; off >>= 1) s += __shfl_xor(s, off);
        if (lane == 0) sump[eh][d] = s;
    }
    __syncthreads();

    {
        const int q = t >> 5, h2 = t & 31;
        const float* eb = enc + (size_t)b * TENC * H_ + hh * 64 + 2 * h2;
        float2 acc[DT];
        #pragma unroll
        for (int d = 0; d < DT; ++d) acc[d] = make_float2(0.f, 0.f);
        for (int e = q * 64; e < q * 64 + 64; e += 4) {
            F4 p4[DT];
            #pragma unroll
            for (int d = 0; d < DT; ++d) p4[d].v = *(const float4*)&sc[d][e];
            #pragma unroll
            for (int j = 0; j < 4; ++j) {
                const float2 ev = *(const float2*)(eb + (size_t)(e + j) * H_);
                #pragma unroll
                for (int d = 0; d < DT; ++d) {
                    acc[d].x = fmaf(p4[d].f[j], ev.x, acc[d].x);
                    acc[d].y = fmaf(p4[d].f[j], ev.y, acc[d].y);
                }
            }
        }
        #pragma unroll
        for (int d = 0; d < DT; ++d) part[q][d][h2] = acc[d];
    }
    __syncthreads();

    if (t < 128) {
        const int d = t >> 5, h2 = t & 31;
        float2 s = make_float2(0.f, 0.f);
        #pragma unroll
        for (int q = 0; q < 16; ++q) {
            const float2 pp = part[q][d][h2];
            s.x += pp.x; s.y += pp.y;
        }
        const float rinv = __builtin_amdgcn_rcpf(sump[0][d] + sump[1][d]);
        s.x *= rinv; s.y *= rinv;
        *(float2*)(out + (size_t)(R0 + d) * H_ + hh * 64 + 2 * h2) = s;
    }
}

extern "C" void kernel_launch(void* const* d_in, const int* in_sizes, int n_in,
                              void* d_out, int out_size, void* d_ws, size_t ws_size,
                              hipStream_t stream) {
    const float* dec = (const float*)d_in[0];
    const float* enc = (const float*)d_in[1];
    const float* Ww  = (const float*)d_in[2];
    const float* Wb  = (const float*)d_in[3];
    const float* Vw  = (const float*)d_in[4];
    float* out = (float*)d_out;

    prep_kernel<<<dim3(TENC / 32, H_ / 32, B_ + 1), dim3(32, 8), 0, stream>>>(
        enc, dec, Ww, Wb, Vw);
    score_kernel<<<dim3(B_ * 128 * 4), dim3(256), 0, stream>>>();
    smctx_kernel<<<dim3(B_ * 128 * 2), dim3(512), 0, stream>>>(enc, out);
}

// Round 8
// 56.706 us; speedup vs baseline: 2.5422x; 2.5422x over previous
//
#include <hip/hip_runtime.h>
#include <math.h>

#define B_    4
#define TDEC  512
#define TENC  1024
#define H_    128
#define DT    4

// exp(2*enc) transposed+packed: [b][eh:2][g:32][e:512][j:4]  (lane-contiguous)
__device__ float g_ebp[(size_t)B_ * 2 * 32 * 512 * 4];   // 2 MB
// per (row-tile rt, g): [V4(4), Ea_d0(4), Ea_d1(4), Ea_d2(4), Ea_d3(4)] = 20 f
__device__ float g_eav[(size_t)B_ * 128 * 32 * 20];      // 1.3 MB
__device__ float g_scr[(size_t)B_ * TDEC * TENC];        // 8 MB raw scores
__device__ float g_sv[1];                                // sum(V_w)

struct EAV { float4 v4, ea0, ea1, ea2, ea3; };
union F4 { float4 v; float f[4]; };

// z<4: transpose enc, store exp(2*enc) -> g_ebp.   z==4: Ea rows + V pack + SV.
__global__ __launch_bounds__(256) void prep_kernel(const float* __restrict__ enc,
                                                   const float* __restrict__ dec,
                                                   const float* __restrict__ Ww,
                                                   const float* __restrict__ Wb,
                                                   const float* __restrict__ Vw) {
    const int z = blockIdx.z;
    const int tx = threadIdx.x, ty = threadIdx.y;
    if (z < B_) {
        __shared__ float tile[32][33];               // [e-local][h-local]
        const int e0 = blockIdx.x * 32, h0 = blockIdx.y * 32, b = z;
        const float* ep = enc + (size_t)b * TENC * H_;
        #pragma unroll
        for (int j = 0; j < 32; j += 8)
            tile[ty + j][tx] = ep[(size_t)(e0 + ty + j) * H_ + h0 + tx];
        __syncthreads();
        // thread (tx,ty): e = e0+tx, g = h0/4+ty -> one float4 store of exp(2x)
        const int g = (h0 >> 2) + ty, e = e0 + tx;
        const int eh = e >> 9, el = e & 511;
        float4 o;
        o.x = __expf(2.f * tile[tx][4 * ty + 0]);
        o.y = __expf(2.f * tile[tx][4 * ty + 1]);
        o.z = __expf(2.f * tile[tx][4 * ty + 2]);
        o.w = __expf(2.f * tile[tx][4 * ty + 3]);
        *(float4*)&g_ebp[((((size_t)b * 2 + eh) * 32 + g) * 512 + el) * 4] = o;
    } else {
        // 128 blocks x 16 rows: Ea = exp(2*(dec @ Ww^T + Wb)); pack Ea & V
        __shared__ float ds[16][H_];
        const int t = ty * 32 + tx;
        const int blk = blockIdx.y * 32 + blockIdx.x;      // 0..127
        const int R0 = blk * 16;
        #pragma unroll
        for (int i = 0; i < 8; ++i) {
            const int f = t + 256 * i;
            ds[f >> 7][f & 127] = dec[(size_t)R0 * H_ + f];
        }
        __syncthreads();
        const int k = t & 127, dd = t >> 7;
        const float* wr = Ww + (size_t)k * H_;
        float s[8];
        #pragma unroll
        for (int j = 0; j < 8; ++j) s[j] = 0.f;
        for (int h = 0; h < H_; h += 4) {
            const float4 w4 = *(const float4*)(wr + h);
            #pragma unroll
            for (int j = 0; j < 8; ++j) {
                const float4 d4 = *(const float4*)&ds[dd + 2 * j][h];
                s[j] = fmaf(w4.x, d4.x, s[j]);
                s[j] = fmaf(w4.y, d4.y, s[j]);
                s[j] = fmaf(w4.z, d4.z, s[j]);
                s[j] = fmaf(w4.w, d4.w, s[j]);
            }
        }
        const float wb = Wb[k], vw = Vw[k];
        const int g = k >> 2, jj = k & 3;
        #pragma unroll
        for (int j = 0; j < 8; ++j) {
            const int rl = dd + 2 * j;          // row within 16-row block
            const int R = R0 + rl;
            const float ea = __expf(2.f * (s[j] + wb));
            g_eav[((size_t)(R >> 2) * 32 + g) * 20 + 4 + (R & 3) * 4 + jj] = ea;
        }
        if (dd == 0) {
            #pragma unroll
            for (int r = 0; r < 4; ++r)
                g_eav[((size_t)((R0 >> 2) + r) * 32 + g) * 20 + jj] = vw;
        }
        if (blk == 0) {
            __shared__ float svp[2];
            if (t < 128) {
                float x = vw;
                #pragma unroll
                for (int off = 32; off; off >>= 1) x += __shfl_xor(x, off);
                if ((t & 63) == 0) svp[t >> 6] = x;
            }
            __syncthreads();
            if (t == 0) g_sv[0] = svp[0] + svp[1];
        }
    }
}

// 4-h fraction combine: sum_i V_i/p_i with p_i = 1 + Ea_i*Eb_i; one rcp.
// Every instruction has <=1 SGPR operand by construction (ea, v4 uniform).
__device__ __forceinline__ float term4(const float4 ea, const float4 v4,
                                       const F4 te, float acc) {
    const float p0 = fmaf(ea.x, te.f[0], 1.f);
    const float p1 = fmaf(ea.y, te.f[1], 1.f);
    const float p2 = fmaf(ea.z, te.f[2], 1.f);
    const float p3 = fmaf(ea.w, te.f[3], 1.f);
    const float p01 = p0 * p1, p23 = p2 * p3;
    const float a  = fmaf(v4.y, p0, v4.x * p1);
    const float bq = fmaf(v4.w, p2, v4.z * p3);
    const float num = fmaf(bq, p01, a * p23);
    return fmaf(num, __builtin_amdgcn_rcpf(p01 * p23), acc);
}

#define DALL(S, TE)                         \
    acc0 = term4(S.ea0, S.v4, TE, acc0);    \
    acc1 = term4(S.ea1, S.v4, TE, acc1);    \
    acc2 = term4(S.ea2, S.v4, TE, acc2);    \
    acc3 = term4(S.ea3, S.v4, TE, acc3);

// grid 1024 = 512 row-tiles x 2 e-halves; block 512; thread owns 1 e, 4 d accs.
// No LDS, no barriers; EAV via uniform s_loads; te: 1 coalesced dwordx4 per g.
__global__ __launch_bounds__(512) void score_kernel() {
    const int t = threadIdx.x, blk = blockIdx.x;
    const int rt = blk >> 1, eh = blk & 1;
    const int b = rt >> 7;
    const int R0 = rt * DT;
    const EAV* epk = (const EAV*)g_eav + (size_t)rt * 32;
    const float* teb = g_ebp + (((size_t)b * 2 + eh) * 32) * 2048 + t * 4;
    const float sv = g_sv[0];

    float acc0 = 0.f, acc1 = 0.f, acc2 = 0.f, acc3 = 0.f;

    EAV A = epk[0];
    F4 tea; tea.v = *(const float4*)teb;

    for (int g = 0; g < 32; g += 2) {
        F4 teb4; teb4.v = *(const float4*)(teb + (size_t)(g + 1) * 2048);
        EAV Bv = epk[g + 1];

        DALL(A, tea);

        const int gn = (g + 2) & 31;         // wrap: last prefetch is a dummy
        tea.v = *(const float4*)(teb + (size_t)gn * 2048);
        A = epk[gn];

        DALL(Bv, teb4);
    }

    float* so = g_scr + (size_t)R0 * TENC + eh * 512 + t;
    so[0 * TENC] = fmaf(-2.f, acc0, sv);
    so[1 * TENC] = fmaf(-2.f, acc1, sv);
    so[2 * TENC] = fmaf(-2.f, acc2, sv);
    so[3 * TENC] = fmaf(-2.f, acc3, sv);
}

// softmax + context: block = (b, row-tile of 4, h-half of 64); no max pass
// (|score| <= |SV| + 2*sum|V_h| ~ 22 -> exp safely in fp32; shift-invariant).
__global__ __launch_bounds__(512, 8) void smctx_kernel(const float* __restrict__ enc,
                                                       float* __restrict__ out) {
    __shared__ float sc[DT][TENC];
    __shared__ float2 part[16][DT][33];
    __shared__ float sump[2][DT];
    const int t = threadIdx.x;
    const int blk = blockIdx.x;
    const int hh = blk & 1, dt = (blk >> 1) & 127, b = blk >> 8;
    const int R0 = b * TDEC + dt * DT;

    {
        const int w = t >> 6, lane = t & 63;
        const int d = w & 3, eh = w >> 2;
        const float* sr = g_scr + (size_t)(R0 + d) * TENC + eh * 512 + lane;
        float s = 0.f;
        #pragma unroll
        for (int i = 0; i < 8; ++i) {
            const float p = __expf(sr[i * 64]);
            sc[d][eh * 512 + lane + i * 64] = p;
            s += p;
        }
        #pragma unroll
        for (int off = 32; off; off >>= 1) s += __shfl_xor(s, off);
        if (lane == 0) sump[eh][d] = s;
    }
    __syncthreads();

    {
        const int q = t >> 5, h2 = t & 31;
        const float* eb = enc + (size_t)b * TENC * H_ + hh * 64 + 2 * h2;
        float2 acc[DT];
        #pragma unroll
        for (int d = 0; d < DT; ++d) acc[d] = make_float2(0.f, 0.f);
        for (int e = q * 64; e < q * 64 + 64; e += 4) {
            F4 p4[DT];
            #pragma unroll
            for (int d = 0; d < DT; ++d) p4[d].v = *(const float4*)&sc[d][e];
            #pragma unroll
            for (int j = 0; j < 4; ++j) {
                const float2 ev = *(const float2*)(eb + (size_t)(e + j) * H_);
                #pragma unroll
                for (int d = 0; d < DT; ++d) {
                    acc[d].x = fmaf(p4[d].f[j], ev.x, acc[d].x);
                    acc[d].y = fmaf(p4[d].f[j], ev.y, acc[d].y);
                }
            }
        }
        #pragma unroll
        for (int d = 0; d < DT; ++d) part[q][d][h2] = acc[d];
    }
    __syncthreads();

    if (t < 128) {
        const int d = t >> 5, h2 = t & 31;
        float2 s = make_float2(0.f, 0.f);
        #pragma unroll
        for (int q = 0; q < 16; ++q) {
            const float2 pp = part[q][d][h2];
            s.x += pp.x; s.y += pp.y;
        }
        const float rinv = __builtin_amdgcn_rcpf(sump[0][d] + sump[1][d]);
        s.x *= rinv; s.y *= rinv;
        *(float2*)(out + (size_t)(R0 + d) * H_ + hh * 64 + 2 * h2) = s;
    }
}

extern "C" void kernel_launch(void* const* d_in, const int* in_sizes, int n_in,
                              void* d_out, int out_size, void* d_ws, size_t ws_size,
                              hipStream_t stream) {
    const float* dec = (const float*)d_in[0];
    const float* enc = (const float*)d_in[1];
    const float* Ww  = (const float*)d_in[2];
    const float* Wb  = (const float*)d_in[3];
    const float* Vw  = (const float*)d_in[4];
    float* out = (float*)d_out;

    prep_kernel<<<dim3(TENC / 32, H_ / 32, B_ + 1), dim3(32, 8), 0, stream>>>(
        enc, dec, Ww, Wb, Vw);
    score_kernel<<<dim3(B_ * 128 * 2), dim3(512), 0, stream>>>();
    smctx_kernel<<<dim3(B_ * 128 * 2), dim3(512), 0, stream>>>(enc, out);
}

// Round 9
// 52.236 us; speedup vs baseline: 2.7598x; 1.0856x over previous
//
#include <hip/hip_runtime.h>
#include <math.h>

#define B_    4
#define TDEC  512
#define TENC  1024
#define H_    128
#define DT    4

// exp(2*enc) transposed+packed: [b][g:32][e:1024][j:4]  (lane-contiguous in e)
__device__ float g_ebp[(size_t)B_ * 32 * TENC * 4];   // 2 MB
// per (row-tile rt, g): [V4(4), Ea_d0(4), Ea_d1(4), Ea_d2(4), Ea_d3(4)] = 20 f
__device__ float g_eav[(size_t)B_ * 128 * 32 * 20];   // 1.3 MB
__device__ float g_sv[1];                             // sum(V_w)

struct EAV { float4 v4, ea0, ea1, ea2, ea3; };
union F4 { float4 v; float f[4]; };

// z<4: transpose enc, store exp(2*enc) -> g_ebp.   z==4: Ea rows + V pack + SV.
__global__ __launch_bounds__(256) void prep_kernel(const float* __restrict__ enc,
                                                   const float* __restrict__ dec,
                                                   const float* __restrict__ Ww,
                                                   const float* __restrict__ Wb,
                                                   const float* __restrict__ Vw) {
    const int z = blockIdx.z;
    const int tx = threadIdx.x, ty = threadIdx.y;
    if (z < B_) {
        __shared__ float tile[32][33];               // [e-local][h-local]
        const int e0 = blockIdx.x * 32, h0 = blockIdx.y * 32, b = z;
        const float* ep = enc + (size_t)b * TENC * H_;
        #pragma unroll
        for (int j = 0; j < 32; j += 8)
            tile[ty + j][tx] = ep[(size_t)(e0 + ty + j) * H_ + h0 + tx];
        __syncthreads();
        // thread (tx,ty): e = e0+tx, g = h0/4+ty -> one float4 store of exp(2x)
        const int g = (h0 >> 2) + ty, e = e0 + tx;
        float4 o;
        o.x = __expf(2.f * tile[tx][4 * ty + 0]);
        o.y = __expf(2.f * tile[tx][4 * ty + 1]);
        o.z = __expf(2.f * tile[tx][4 * ty + 2]);
        o.w = __expf(2.f * tile[tx][4 * ty + 3]);
        *(float4*)&g_ebp[(((size_t)b * 32 + g) * TENC + e) * 4] = o;
    } else {
        // 128 blocks x 16 rows: Ea = exp(2*(dec @ Ww^T + Wb)); pack Ea & V
        __shared__ float ds[16][H_];
        const int t = ty * 32 + tx;
        const int blk = blockIdx.y * 32 + blockIdx.x;      // 0..127
        const int R0 = blk * 16;
        #pragma unroll
        for (int i = 0; i < 8; ++i) {
            const int f = t + 256 * i;
            ds[f >> 7][f & 127] = dec[(size_t)R0 * H_ + f];
        }
        __syncthreads();
        const int k = t & 127, dd = t >> 7;
        const float* wr = Ww + (size_t)k * H_;
        float s[8];
        #pragma unroll
        for (int j = 0; j < 8; ++j) s[j] = 0.f;
        for (int h = 0; h < H_; h += 4) {
            const float4 w4 = *(const float4*)(wr + h);
            #pragma unroll
            for (int j = 0; j < 8; ++j) {
                const float4 d4 = *(const float4*)&ds[dd + 2 * j][h];
                s[j] = fmaf(w4.x, d4.x, s[j]);
                s[j] = fmaf(w4.y, d4.y, s[j]);
                s[j] = fmaf(w4.z, d4.z, s[j]);
                s[j] = fmaf(w4.w, d4.w, s[j]);
            }
        }
        const float wb = Wb[k], vw = Vw[k];
        const int g = k >> 2, jj = k & 3;
        #pragma unroll
        for (int j = 0; j < 8; ++j) {
            const int rl = dd + 2 * j;          // row within 16-row block
            const int R = R0 + rl;
            const float ea = __expf(2.f * (s[j] + wb));
            g_eav[((size_t)(R >> 2) * 32 + g) * 20 + 4 + (R & 3) * 4 + jj] = ea;
        }
        if (dd == 0) {
            #pragma unroll
            for (int r = 0; r < 4; ++r)
                g_eav[((size_t)((R0 >> 2) + r) * 32 + g) * 20 + jj] = vw;
        }
        if (blk == 0) {
            __shared__ float svp[2];
            if (t < 128) {
                float x = vw;
                #pragma unroll
                for (int off = 32; off; off >>= 1) x += __shfl_xor(x, off);
                if ((t & 63) == 0) svp[t >> 6] = x;
            }
            __syncthreads();
            if (t == 0) g_sv[0] = svp[0] + svp[1];
        }
    }
}

// 4-h fraction combine: sum_i V_i/p_i with p_i = 1 + Ea_i*Eb_i; one rcp.
__device__ __forceinline__ float term4(const float4 ea, const float4 v4,
                                       const F4 te, float acc) {
    const float p0 = fmaf(ea.x, te.f[0], 1.f);
    const float p1 = fmaf(ea.y, te.f[1], 1.f);
    const float p2 = fmaf(ea.z, te.f[2], 1.f);
    const float p3 = fmaf(ea.w, te.f[3], 1.f);
    const float p01 = p0 * p1, p23 = p2 * p3;
    const float a  = fmaf(v4.y, p0, v4.x * p1);
    const float bq = fmaf(v4.w, p2, v4.z * p3);
    const float num = fmaf(bq, p01, a * p23);
    return fmaf(num, __builtin_amdgcn_rcpf(p01 * p23), acc);
}

#define DALL(S, TE)                         \
    acc0 = term4(S.ea0, S.v4, TE, acc0);    \
    acc1 = term4(S.ea1, S.v4, TE, acc1);    \
    acc2 = term4(S.ea2, S.v4, TE, acc2);    \
    acc3 = term4(S.ea3, S.v4, TE, acc3);

// Fused: score + softmax(sum-only) + context + write.  Block = 1 row-tile
// (4 rows), 1024 threads (thread owns 1 e); grid 512 -> 2 blocks/CU,
// 8 waves/SIMD.  3 barriers total; no g_scr round trip.
__global__ __launch_bounds__(1024, 8) void fused_kernel(const float* __restrict__ enc,
                                                        float* __restrict__ out) {
    __shared__ float sc[DT][TENC];          // p = exp(score)      (16 KB)
    __shared__ float2 part[16][DT][64];     // context partials    (32 KB)
    __shared__ float wsum[16][DT];
    __shared__ float rsum[DT];

    const int t = threadIdx.x;
    const int rt = blockIdx.x;              // 0..511
    const int b = rt >> 7;
    const int R0 = rt * DT;
    const EAV* epk = (const EAV*)g_eav + (size_t)rt * 32;
    const float* teb = g_ebp + (size_t)b * 32 * (TENC * 4) + t * 4;
    const float sv = g_sv[0];

    // --- Phase 1: scores (barrier-free; EAV via uniform s_loads) ---
    float acc0 = 0.f, acc1 = 0.f, acc2 = 0.f, acc3 = 0.f;
    EAV A = epk[0];
    F4 tea; tea.v = *(const float4*)teb;

    for (int g = 0; g < 32; g += 2) {
        F4 teb4; teb4.v = *(const float4*)(teb + (size_t)(g + 1) * (TENC * 4));
        EAV Bv = epk[g + 1];

        DALL(A, tea);

        const int gn = (g + 2) & 31;        // wrap: last prefetch is a dummy
        tea.v = *(const float4*)(teb + (size_t)gn * (TENC * 4));
        A = epk[gn];

        DALL(Bv, teb4);
    }

    // --- Phase 2: p = exp(score); stash + per-wave partial sums ---
    const float q0 = __expf(fmaf(-2.f, acc0, sv));
    const float q1 = __expf(fmaf(-2.f, acc1, sv));
    const float q2 = __expf(fmaf(-2.f, acc2, sv));
    const float q3 = __expf(fmaf(-2.f, acc3, sv));
    sc[0][t] = q0; sc[1][t] = q1; sc[2][t] = q2; sc[3][t] = q3;

    float s0 = q0, s1 = q1, s2 = q2, s3 = q3;
    #pragma unroll
    for (int off = 32; off; off >>= 1) {
        s0 += __shfl_xor(s0, off);
        s1 += __shfl_xor(s1, off);
        s2 += __shfl_xor(s2, off);
        s3 += __shfl_xor(s3, off);
    }
    {
        const int w = t >> 6, lane = t & 63;
        if (lane == 0) { wsum[w][0] = s0; wsum[w][1] = s1; wsum[w][2] = s2; wsum[w][3] = s3; }
    }
    __syncthreads();
    if (t < 64) {                            // lane = w'*4 + d
        float x = wsum[t >> 2][t & 3];
        #pragma unroll
        for (int off = 4; off < 64; off <<= 1) x += __shfl_xor(x, off);
        if (t < 4) rsum[t] = x;
    }

    // --- Phase 3: context partials; thread = (q = e-slice of 64, h2) ---
    {
        const int q = t >> 6, h2 = t & 63;
        const float* eb = enc + (size_t)b * TENC * H_ + 2 * h2;
        float2 a0 = {0.f, 0.f}, a1 = {0.f, 0.f}, a2 = {0.f, 0.f}, a3 = {0.f, 0.f};
        const int e0 = q * 64;
        for (int e = e0; e < e0 + 64; e += 4) {
            F4 u0, u1, u2, u3;
            u0.v = *(const float4*)&sc[0][e];
            u1.v = *(const float4*)&sc[1][e];
            u2.v = *(const float4*)&sc[2][e];
            u3.v = *(const float4*)&sc[3][e];
            #pragma unroll
            for (int j = 0; j < 4; ++j) {
                const float2 ev = *(const float2*)(eb + (size_t)(e + j) * H_);
                a0.x = fmaf(u0.f[j], ev.x, a0.x); a0.y = fmaf(u0.f[j], ev.y, a0.y);
                a1.x = fmaf(u1.f[j], ev.x, a1.x); a1.y = fmaf(u1.f[j], ev.y, a1.y);
                a2.x = fmaf(u2.f[j], ev.x, a2.x); a2.y = fmaf(u2.f[j], ev.y, a2.y);
                a3.x = fmaf(u3.f[j], ev.x, a3.x); a3.y = fmaf(u3.f[j], ev.y, a3.y);
            }
        }
        part[q][0][h2] = a0; part[q][1][h2] = a1;
        part[q][2][h2] = a2; part[q][3][h2] = a3;
    }
    __syncthreads();

    // --- Phase 4: merge 16 slices, divide, write ---
    if (t < 256) {
        const int d = t >> 6, h2 = t & 63;
        float2 s = {0.f, 0.f};
        #pragma unroll
        for (int q = 0; q < 16; ++q) {
            const float2 pp = part[q][d][h2];
            s.x += pp.x; s.y += pp.y;
        }
        const float rinv = __builtin_amdgcn_rcpf(rsum[d]);
        s.x *= rinv; s.y *= rinv;
        *(float2*)(out + (size_t)(R0 + d) * H_ + 2 * h2) = s;
    }
}

extern "C" void kernel_launch(void* const* d_in, const int* in_sizes, int n_in,
                              void* d_out, int out_size, void* d_ws, size_t ws_size,
                              hipStream_t stream) {
    const float* dec = (const float*)d_in[0];
    const float* enc = (const float*)d_in[1];
    const float* Ww  = (const float*)d_in[2];
    const float* Wb  = (const float*)d_in[3];
    const float* Vw  = (const float*)d_in[4];
    float* out = (float*)d_out;

    prep_kernel<<<dim3(TENC / 32, H_ / 32, B_ + 1), dim3(32, 8), 0, stream>>>(
        enc, dec, Ww, Wb, Vw);
    fused_kernel<<<dim3(B_ * 128), dim3(1024), 0, stream>>>(enc, out);
}